// Round 1
// baseline (167.452 us; speedup 1.0000x reference)
//
#include <hip/hip_runtime.h>
#include <math.h>

#define D_PET 128
#define NK    256
#define NB    2048
#define NBATCH 16

__device__ __forceinline__ float silu(float x) {
    return x / (1.0f + expf(-x));
}

__device__ __forceinline__ int lower_bound_dev(const int* a, int n, int v) {
    int lo = 0, hi = n;
    while (lo < hi) {
        int m = (lo + hi) >> 1;
        if (a[m] < v) lo = m + 1; else hi = m;
    }
    return lo;
}

// ---------------------------------------------------------------------------
// Kernel 1: filt[b,k,:] = MLP(kv[b,k,:])   (unchanged from previous round)
// ---------------------------------------------------------------------------
#define MJ 8   // k-vectors per block
__global__ void mlp_kernel(const float* __restrict__ kvec,
                           const float* __restrict__ W1, const float* __restrict__ b1,
                           const float* __restrict__ W2, const float* __restrict__ b2,
                           const float* __restrict__ W3, const float* __restrict__ b3,
                           float* __restrict__ filt) {
    int bk0 = blockIdx.x * MJ;        // first (b*NK+k) of this block
    int d   = threadIdx.x & (D_PET - 1);
    int jg  = threadIdx.x >> 7;       // 0/1; this thread handles j = jg*4 + 0..3

    __shared__ float kv_s[MJ * 3];
    __shared__ float x_lds[D_PET * MJ];   // [e][j] layout, 4 KB

    if (threadIdx.x < MJ * 3) kv_s[threadIdx.x] = kvec[bk0 * 3 + threadIdx.x];
    __syncthreads();

    // ---- layer 1: 3 -> 128, silu ----
    float w10 = W1[0 * D_PET + d], w11 = W1[1 * D_PET + d], w12 = W1[2 * D_PET + d];
    float bb1 = b1[d];
    float4 x1;
    {
        float* xp = (float*)&x1;
#pragma unroll
        for (int i = 0; i < 4; i++) {
            int j = jg * 4 + i;
            float a = bb1;
            a = fmaf(kv_s[j * 3 + 0], w10, a);
            a = fmaf(kv_s[j * 3 + 1], w11, a);
            a = fmaf(kv_s[j * 3 + 2], w12, a);
            xp[i] = silu(a);
        }
    }
    *(float4*)&x_lds[(d << 3) + (jg << 2)] = x1;
    __syncthreads();

    // ---- layer 2: 128 -> 128, silu ----
    float acc0 = b2[d], acc1 = acc0, acc2 = acc0, acc3 = acc0;
#pragma unroll 4
    for (int e = 0; e < D_PET; e++) {
        float w = W2[e * D_PET + d];
        float4 xv = *(const float4*)&x_lds[(e << 3) + (jg << 2)];
        acc0 = fmaf(xv.x, w, acc0);
        acc1 = fmaf(xv.y, w, acc1);
        acc2 = fmaf(xv.z, w, acc2);
        acc3 = fmaf(xv.w, w, acc3);
    }
    float4 x2 = make_float4(silu(acc0), silu(acc1), silu(acc2), silu(acc3));
    __syncthreads();
    *(float4*)&x_lds[(d << 3) + (jg << 2)] = x2;
    __syncthreads();

    // ---- layer 3: 128 -> 128 ----
    float o0 = b3[d], o1 = o0, o2 = o0, o3 = o0;
#pragma unroll 4
    for (int e = 0; e < D_PET; e++) {
        float w = W3[e * D_PET + d];
        float4 xv = *(const float4*)&x_lds[(e << 3) + (jg << 2)];
        o0 = fmaf(xv.x, w, o0);
        o1 = fmaf(xv.y, w, o1);
        o2 = fmaf(xv.z, w, o2);
        o3 = fmaf(xv.w, w, o3);
    }
    float out4[4] = {o0, o1, o2, o3};
#pragma unroll
    for (int i = 0; i < 4; i++) {
        int j = jg * 4 + i;
        filt[(size_t)(bk0 + j) * D_PET + d] = out4[i];
    }
}

// ---------------------------------------------------------------------------
// Kernel 2: interleaved cos/sin table cs2[n][k] = {cos, sin}
// grid = NB blocks, NK threads
// ---------------------------------------------------------------------------
__global__ void phase_kernel(const float* __restrict__ kvec,
                             const float* __restrict__ pos,
                             const int* __restrict__ batch,
                             float2* __restrict__ cs2) {
    int n = blockIdx.x;
    int k = threadIdx.x;
    int b = batch[n];
    float p0 = pos[n * 3 + 0], p1 = pos[n * 3 + 1], p2 = pos[n * 3 + 2];
    const float* kv = kvec + ((size_t)b * NK + k) * 3;
    float ph = p0 * kv[0] + p1 * kv[1] + p2 * kv[2];
    float s, c;
    sincosf(ph, &s, &c);
    cs2[(size_t)n * NK + k] = make_float2(c, s);
}

// ---------------------------------------------------------------------------
// Kernel 3 (v2): t2[b,k,d] = (sum_{n in b} e^{-i phi_nk} h[n,d]) * filt[b,k,d]
// grid = 16 * (256/4) = 1024 blocks, 256 threads.
// Block owns (b, 4 k's). Thread: d = tid&127, kg = tid>>7 -> k = k0+kg*2 +{0,1}.
// Barrier-free, LDS-free: per atom 1 coalesced h load + 1 float4 cs load + 4 fma.
// ---------------------------------------------------------------------------
#define SKQ 4   // k per block
__global__ void __launch_bounds__(256) s_kernel(
                         const float* __restrict__ h,
                         const float* __restrict__ cs2,   // [n][k] {c,s} as floats
                         const int* __restrict__ batch,
                         const float* __restrict__ filt,
                         float2* __restrict__ t2) {
    const int tiles = NK / SKQ;                 // 64
    int b  = blockIdx.x / tiles;
    int k0 = (blockIdx.x % tiles) * SKQ;
    int d  = threadIdx.x & (D_PET - 1);
    int kg = threadIdx.x >> 7;                  // 0/1
    int kq = k0 + kg * 2;                       // this thread: k = kq, kq+1

    int lo = lower_bound_dev(batch, NB, b);
    int hi = lower_bound_dev(batch, NB, b + 1);

    float sre0 = 0.f, sim0 = 0.f, sre1 = 0.f, sim1 = 0.f;
    const float* csp = cs2 + 2 * kq;

#define S_BODY(nn)                                                         \
    {                                                                      \
        float hv = h[(size_t)(nn) * D_PET + d];                            \
        float4 q = *(const float4*)(csp + (size_t)(nn) * (2 * NK));        \
        sre0 = fmaf(q.x, hv, sre0); sim0 = fmaf(-q.y, hv, sim0);           \
        sre1 = fmaf(q.z, hv, sre1); sim1 = fmaf(-q.w, hv, sim1);           \
    }

    int n = lo;
    for (; n + 3 < hi; n += 4) {
        S_BODY(n); S_BODY(n + 1); S_BODY(n + 2); S_BODY(n + 3);
    }
    for (; n < hi; n++) S_BODY(n);
#undef S_BODY

    size_t idx = ((size_t)b * NK + kq) * D_PET + d;
    float f0 = filt[idx];
    float f1 = filt[idx + D_PET];
    t2[idx]         = make_float2(sre0 * f0, sim0 * f0);
    t2[idx + D_PET] = make_float2(sre1 * f1, sim1 * f1);
}

// ---------------------------------------------------------------------------
// Kernel 4 (v2): out[n,d] = sum_k e^{+i phi_nk} * t2[batch[n],k,d]
// grid = NB/4 = 512 blocks, 256 threads. Block owns 4 consecutive atoms.
// Thread: d = tid&127, ag = tid>>7 -> atoms n0+2ag, n0+2ag+1. Full k in regs.
// Barrier-free, LDS-free; t2 served from L2 (XCD-contiguous swizzle keeps the
// per-XCD working set to ~2 batches' t slices, ~512 KB << 4 MB L2).
// ---------------------------------------------------------------------------
__global__ void __launch_bounds__(256) out_kernel(
                           const float* __restrict__ cs2,
                           const int* __restrict__ batch,
                           const float2* __restrict__ t2,
                           float* __restrict__ out, int interleaved) {
    int i = blockIdx.x;
    // bijective XCD-contiguous swizzle (gridDim.x = 512, divisible by 8)
    int v = (i & 7) * (int)(gridDim.x >> 3) + (i >> 3);
    int n0 = v * 4;
    int d  = threadIdx.x & (D_PET - 1);
    int ag = threadIdx.x >> 7;                  // 0/1
    int nA = n0 + ag * 2;
    int nB = nA + 1;

    int bA = batch[nA], bB = batch[nB];
    const float2* tA = t2 + (size_t)bA * NK * D_PET + d;
    const float2* tB = t2 + (size_t)bB * NK * D_PET + d;
    const float*  cA = cs2 + (size_t)nA * 2 * NK;
    const float*  cB = cs2 + (size_t)nB * 2 * NK;

    float oreA = 0.f, oimA = 0.f, oreB = 0.f, oimB = 0.f;

#pragma unroll 4
    for (int k = 0; k < NK; k += 2) {
        float4 qa = *(const float4*)(cA + 2 * k);   // {c_k, s_k, c_k1, s_k1}
        float4 qb = *(const float4*)(cB + 2 * k);
        float2 a0 = tA[(size_t)k * D_PET];
        float2 a1 = tA[(size_t)(k + 1) * D_PET];
        float2 b0 = tB[(size_t)k * D_PET];
        float2 b1 = tB[(size_t)(k + 1) * D_PET];

        oreA = fmaf(qa.x, a0.x, oreA); oreA = fmaf(-qa.y, a0.y, oreA);
        oimA = fmaf(qa.x, a0.y, oimA); oimA = fmaf(qa.y, a0.x, oimA);
        oreA = fmaf(qa.z, a1.x, oreA); oreA = fmaf(-qa.w, a1.y, oreA);
        oimA = fmaf(qa.z, a1.y, oimA); oimA = fmaf(qa.w, a1.x, oimA);

        oreB = fmaf(qb.x, b0.x, oreB); oreB = fmaf(-qb.y, b0.y, oreB);
        oimB = fmaf(qb.x, b0.y, oimB); oimB = fmaf(qb.y, b0.x, oimB);
        oreB = fmaf(qb.z, b1.x, oreB); oreB = fmaf(-qb.w, b1.y, oreB);
        oimB = fmaf(qb.z, b1.y, oimB); oimB = fmaf(qb.w, b1.x, oimB);
    }

    if (interleaved) {
        ((float2*)out)[(size_t)nA * D_PET + d] = make_float2(oreA, oimA);
        ((float2*)out)[(size_t)nB * D_PET + d] = make_float2(oreB, oimB);
    } else {
        out[(size_t)nA * D_PET + d] = oreA;
        out[(size_t)nB * D_PET + d] = oreB;
    }
}

// ---------------------------------------------------------------------------
extern "C" void kernel_launch(void* const* d_in, const int* in_sizes, int n_in,
                              void* d_out, int out_size, void* d_ws, size_t ws_size,
                              hipStream_t stream) {
    const float* kvec = (const float*)d_in[0];   // [16,256,3]
    const float* pos  = (const float*)d_in[1];   // [2048,3]
    const float* h    = (const float*)d_in[2];   // [2048,128]
    const float* W1   = (const float*)d_in[3];
    const float* b1   = (const float*)d_in[4];
    const float* W2   = (const float*)d_in[5];
    const float* b2   = (const float*)d_in[6];
    const float* W3   = (const float*)d_in[7];
    const float* b3   = (const float*)d_in[8];
    const int*   batch = (const int*)d_in[9];    // [2048]

    float* ws   = (float*)d_ws;
    float* filt = ws;                                    // 16*256*128 floats
    float* cs2  = filt + (size_t)NBATCH * NK * D_PET;    // 2048*256*2 floats
    float2* t2  = (float2*)(cs2 + (size_t)NB * NK * 2);  // 16*256*128 float2

    int interleaved = (out_size == NB * D_PET * 2) ? 1 : 0;

    mlp_kernel<<<NBATCH * NK / MJ, 256, 0, stream>>>(kvec, W1, b1, W2, b2, W3, b3, filt);
    phase_kernel<<<NB, NK, 0, stream>>>(kvec, pos, batch, (float2*)cs2);
    s_kernel<<<NBATCH * (NK / SKQ), 256, 0, stream>>>(h, cs2, batch, filt, t2);
    out_kernel<<<NB / 4, 256, 0, stream>>>(cs2, batch, t2, (float*)d_out, interleaved);
}

// Round 2
// 156.323 us; speedup vs baseline: 1.0712x; 1.0712x over previous
//
#include <hip/hip_runtime.h>
#include <math.h>

#define D_PET 128
#define NK    256
#define NB    2048
#define NBATCH 16

__device__ __forceinline__ float silu(float x) {
    return x / (1.0f + expf(-x));
}

__device__ __forceinline__ int lower_bound_dev(const int* a, int n, int v) {
    int lo = 0, hi = n;
    while (lo < hi) {
        int m = (lo + hi) >> 1;
        if (a[m] < v) lo = m + 1; else hi = m;
    }
    return lo;
}

// ---------------------------------------------------------------------------
// Kernel 1 (fused): blocks [0, MLP_BLOCKS) run the MLP, the rest compute the
// interleaved cos/sin table. The two are independent (mlp: kvec+W,
// phase: kvec+pos+batch) -> one launch, no gap.
// ---------------------------------------------------------------------------
#define MJ 8   // k-vectors per mlp block
#define MLP_BLOCKS (NBATCH * NK / MJ)   // 512

__global__ void __launch_bounds__(256) prep_kernel(
                           const float* __restrict__ kvec,
                           const float* __restrict__ W1, const float* __restrict__ b1,
                           const float* __restrict__ W2, const float* __restrict__ b2,
                           const float* __restrict__ W3, const float* __restrict__ b3,
                           float* __restrict__ filt,
                           const float* __restrict__ pos,
                           const int* __restrict__ batch,
                           float2* __restrict__ cs2) {
    __shared__ float kv_s[MJ * 3];
    __shared__ float x_lds[D_PET * MJ];   // [e][j] layout, 4 KB

    if (blockIdx.x >= MLP_BLOCKS) {
        // ---- phase table: one atom per block, one k per thread ----
        int n = blockIdx.x - MLP_BLOCKS;
        int k = threadIdx.x;
        int b = batch[n];
        float p0 = pos[n * 3 + 0], p1 = pos[n * 3 + 1], p2 = pos[n * 3 + 2];
        const float* kv = kvec + ((size_t)b * NK + k) * 3;
        float ph = p0 * kv[0] + p1 * kv[1] + p2 * kv[2];
        float s, c;
        sincosf(ph, &s, &c);
        cs2[(size_t)n * NK + k] = make_float2(c, s);
        return;
    }

    // ---- MLP: filt[b,k,:] ----
    int bk0 = blockIdx.x * MJ;        // first (b*NK+k) of this block
    int d   = threadIdx.x & (D_PET - 1);
    int jg  = threadIdx.x >> 7;       // 0/1; this thread handles j = jg*4 + 0..3

    if (threadIdx.x < MJ * 3) kv_s[threadIdx.x] = kvec[bk0 * 3 + threadIdx.x];
    __syncthreads();

    // layer 1: 3 -> 128, silu
    float w10 = W1[0 * D_PET + d], w11 = W1[1 * D_PET + d], w12 = W1[2 * D_PET + d];
    float bb1 = b1[d];
    float4 x1;
    {
        float* xp = (float*)&x1;
#pragma unroll
        for (int i = 0; i < 4; i++) {
            int j = jg * 4 + i;
            float a = bb1;
            a = fmaf(kv_s[j * 3 + 0], w10, a);
            a = fmaf(kv_s[j * 3 + 1], w11, a);
            a = fmaf(kv_s[j * 3 + 2], w12, a);
            xp[i] = silu(a);
        }
    }
    *(float4*)&x_lds[(d << 3) + (jg << 2)] = x1;
    __syncthreads();

    // layer 2: 128 -> 128, silu
    float acc0 = b2[d], acc1 = acc0, acc2 = acc0, acc3 = acc0;
#pragma unroll 8
    for (int e = 0; e < D_PET; e++) {
        float w = W2[e * D_PET + d];
        float4 xv = *(const float4*)&x_lds[(e << 3) + (jg << 2)];
        acc0 = fmaf(xv.x, w, acc0);
        acc1 = fmaf(xv.y, w, acc1);
        acc2 = fmaf(xv.z, w, acc2);
        acc3 = fmaf(xv.w, w, acc3);
    }
    float4 x2 = make_float4(silu(acc0), silu(acc1), silu(acc2), silu(acc3));
    __syncthreads();
    *(float4*)&x_lds[(d << 3) + (jg << 2)] = x2;
    __syncthreads();

    // layer 3: 128 -> 128
    float o0 = b3[d], o1 = o0, o2 = o0, o3 = o0;
#pragma unroll 8
    for (int e = 0; e < D_PET; e++) {
        float w = W3[e * D_PET + d];
        float4 xv = *(const float4*)&x_lds[(e << 3) + (jg << 2)];
        o0 = fmaf(xv.x, w, o0);
        o1 = fmaf(xv.y, w, o1);
        o2 = fmaf(xv.z, w, o2);
        o3 = fmaf(xv.w, w, o3);
    }
    float out4[4] = {o0, o1, o2, o3};
#pragma unroll
    for (int i = 0; i < 4; i++) {
        int j = jg * 4 + i;
        filt[(size_t)(bk0 + j) * D_PET + d] = out4[i];
    }
}

// ---------------------------------------------------------------------------
// Kernel 2 (v3): t2[b,k,d] = (sum_{n in b} e^{-i phi_nk} h[n,d]) * filt[b,k,d]
// grid = 16 * 64 = 1024 blocks (4/CU), 256 threads. Thread owns (2 k's, d).
// Manual 8-wide atom batches: 16 independent loads in flight before any FMA.
// ---------------------------------------------------------------------------
#define SKQ 4   // k per block
__global__ void __launch_bounds__(256) s_kernel(
                         const float* __restrict__ h,
                         const float* __restrict__ cs2,   // [n][k] {c,s}
                         const int* __restrict__ batch,
                         const float* __restrict__ filt,
                         float2* __restrict__ t2) {
    const int tiles = NK / SKQ;                 // 64
    int b  = blockIdx.x / tiles;
    int k0 = (blockIdx.x % tiles) * SKQ;
    int d  = threadIdx.x & (D_PET - 1);
    int kg = threadIdx.x >> 7;                  // 0/1
    int kq = k0 + kg * 2;                       // this thread: k = kq, kq+1

    int lo = lower_bound_dev(batch, NB, b);
    int hi = lower_bound_dev(batch, NB, b + 1);

    float sre0 = 0.f, sim0 = 0.f, sre1 = 0.f, sim1 = 0.f;
    // cs row as float4 ({c,s} for 2 consecutive k); 2*kq is 4-float aligned
    const float4* csp = (const float4*)(cs2 + 2 * kq);
    const int csstride = NK / 2;                // float4 per atom row

    int n = lo;
    for (; n + 7 < hi; n += 8) {
        // issue all 16 loads, then fma
        float hv0 = h[(size_t)(n + 0) * D_PET + d];
        float hv1 = h[(size_t)(n + 1) * D_PET + d];
        float hv2 = h[(size_t)(n + 2) * D_PET + d];
        float hv3 = h[(size_t)(n + 3) * D_PET + d];
        float hv4 = h[(size_t)(n + 4) * D_PET + d];
        float hv5 = h[(size_t)(n + 5) * D_PET + d];
        float hv6 = h[(size_t)(n + 6) * D_PET + d];
        float hv7 = h[(size_t)(n + 7) * D_PET + d];
        float4 q0 = csp[(size_t)(n + 0) * csstride];
        float4 q1 = csp[(size_t)(n + 1) * csstride];
        float4 q2 = csp[(size_t)(n + 2) * csstride];
        float4 q3 = csp[(size_t)(n + 3) * csstride];
        float4 q4 = csp[(size_t)(n + 4) * csstride];
        float4 q5 = csp[(size_t)(n + 5) * csstride];
        float4 q6 = csp[(size_t)(n + 6) * csstride];
        float4 q7 = csp[(size_t)(n + 7) * csstride];
#define S_FMA(q, hv)                                              \
        sre0 = fmaf(q.x, hv, sre0); sim0 = fmaf(-q.y, hv, sim0);  \
        sre1 = fmaf(q.z, hv, sre1); sim1 = fmaf(-q.w, hv, sim1);
        S_FMA(q0, hv0) S_FMA(q1, hv1) S_FMA(q2, hv2) S_FMA(q3, hv3)
        S_FMA(q4, hv4) S_FMA(q5, hv5) S_FMA(q6, hv6) S_FMA(q7, hv7)
    }
    for (; n < hi; n++) {
        float hv = h[(size_t)n * D_PET + d];
        float4 q = csp[(size_t)n * csstride];
        S_FMA(q, hv)
    }
#undef S_FMA

    size_t idx = ((size_t)b * NK + kq) * D_PET + d;
    float f0 = filt[idx];
    float f1 = filt[idx + D_PET];
    t2[idx]         = make_float2(sre0 * f0, sim0 * f0);
    t2[idx + D_PET] = make_float2(sre1 * f1, sim1 * f1);
}

// ---------------------------------------------------------------------------
// Kernel 3 (v3): out[n,d] = sum_k e^{+i phi_nk} * t2[batch[n],k,d]
// grid = NB/2 = 1024 blocks (4/CU), 256 threads. Thread owns ONE (atom, d):
// d = tid&127, atom = n0 + (tid>>7). Full k loop, manual 8-k batches:
// 12 independent loads in flight (4 uniform cs float4 + 8 strided t float2).
// XCD-contiguous swizzle: each XCD sees ~2 batches' t slices (~512 KB in L2).
// ---------------------------------------------------------------------------
__global__ void __launch_bounds__(256) out_kernel(
                           const float* __restrict__ cs2,
                           const int* __restrict__ batch,
                           const float2* __restrict__ t2,
                           float* __restrict__ out, int interleaved) {
    int i = blockIdx.x;
    // bijective XCD-contiguous swizzle (gridDim.x = 1024, divisible by 8)
    int v = (i & 7) * (int)(gridDim.x >> 3) + (i >> 3);
    int d  = threadIdx.x & (D_PET - 1);
    int ag = threadIdx.x >> 7;                  // 0/1
    int n  = v * 2 + ag;

    int b = batch[n];
    const float2* tp = t2 + (size_t)b * NK * D_PET + d;
    const float4* cp = (const float4*)(cs2 + (size_t)n * 2 * NK);

    float ore = 0.f, oim = 0.f;

#pragma unroll 2
    for (int k = 0; k < NK; k += 8) {
        float4 q0 = cp[(k >> 1) + 0];
        float4 q1 = cp[(k >> 1) + 1];
        float4 q2 = cp[(k >> 1) + 2];
        float4 q3 = cp[(k >> 1) + 3];
        float2 t0 = tp[(size_t)(k + 0) * D_PET];
        float2 t1 = tp[(size_t)(k + 1) * D_PET];
        float2 t2v = tp[(size_t)(k + 2) * D_PET];
        float2 t3 = tp[(size_t)(k + 3) * D_PET];
        float2 t4 = tp[(size_t)(k + 4) * D_PET];
        float2 t5 = tp[(size_t)(k + 5) * D_PET];
        float2 t6 = tp[(size_t)(k + 6) * D_PET];
        float2 t7 = tp[(size_t)(k + 7) * D_PET];
#define O_FMA(q, ta, tb)                                          \
        ore = fmaf(q.x, ta.x, ore); ore = fmaf(-q.y, ta.y, ore);  \
        oim = fmaf(q.x, ta.y, oim); oim = fmaf(q.y, ta.x, oim);   \
        ore = fmaf(q.z, tb.x, ore); ore = fmaf(-q.w, tb.y, ore);  \
        oim = fmaf(q.z, tb.y, oim); oim = fmaf(q.w, tb.x, oim);
        O_FMA(q0, t0, t1) O_FMA(q1, t2v, t3) O_FMA(q2, t4, t5) O_FMA(q3, t6, t7)
#undef O_FMA
    }

    if (interleaved) {
        ((float2*)out)[(size_t)n * D_PET + d] = make_float2(ore, oim);
    } else {
        out[(size_t)n * D_PET + d] = ore;
    }
}

// ---------------------------------------------------------------------------
extern "C" void kernel_launch(void* const* d_in, const int* in_sizes, int n_in,
                              void* d_out, int out_size, void* d_ws, size_t ws_size,
                              hipStream_t stream) {
    const float* kvec = (const float*)d_in[0];   // [16,256,3]
    const float* pos  = (const float*)d_in[1];   // [2048,3]
    const float* h    = (const float*)d_in[2];   // [2048,128]
    const float* W1   = (const float*)d_in[3];
    const float* b1   = (const float*)d_in[4];
    const float* W2   = (const float*)d_in[5];
    const float* b2   = (const float*)d_in[6];
    const float* W3   = (const float*)d_in[7];
    const float* b3   = (const float*)d_in[8];
    const int*   batch = (const int*)d_in[9];    // [2048]

    float* ws   = (float*)d_ws;
    float* filt = ws;                                    // 16*256*128 floats
    float* cs2  = filt + (size_t)NBATCH * NK * D_PET;    // 2048*256*2 floats
    float2* t2  = (float2*)(cs2 + (size_t)NB * NK * 2);  // 16*256*128 float2

    int interleaved = (out_size == NB * D_PET * 2) ? 1 : 0;

    prep_kernel<<<MLP_BLOCKS + NB, 256, 0, stream>>>(kvec, W1, b1, W2, b2, W3, b3,
                                                     filt, pos, batch, (float2*)cs2);
    s_kernel<<<NBATCH * (NK / SKQ), 256, 0, stream>>>(h, cs2, batch, filt, t2);
    out_kernel<<<NB / 2, 256, 0, stream>>>(cs2, batch, t2, (float*)d_out, interleaved);
}

// Round 3
// 155.554 us; speedup vs baseline: 1.0765x; 1.0049x over previous
//
#include <hip/hip_runtime.h>
#include <math.h>

#define D_PET 128
#define NK    256
#define NB    2048
#define NBATCH 16

__device__ __forceinline__ float silu(float x) {
    return x / (1.0f + expf(-x));
}

__device__ __forceinline__ int lower_bound_dev(const int* a, int n, int v) {
    int lo = 0, hi = n;
    while (lo < hi) {
        int m = (lo + hi) >> 1;
        if (a[m] < v) lo = m + 1; else hi = m;
    }
    return lo;
}

// ---------------------------------------------------------------------------
// Kernel 1 (fused): blocks [0, MLP_BLOCKS) run the MLP, the rest the phase
// table. W2/W3 loads batched 8-wide with sched_barrier to force MLP of loads.
// ---------------------------------------------------------------------------
#define MJ 8
#define MLP_BLOCKS (NBATCH * NK / MJ)   // 512

__global__ void __launch_bounds__(256) prep_kernel(
                           const float* __restrict__ kvec,
                           const float* __restrict__ W1, const float* __restrict__ b1,
                           const float* __restrict__ W2, const float* __restrict__ b2,
                           const float* __restrict__ W3, const float* __restrict__ b3,
                           float* __restrict__ filt,
                           const float* __restrict__ pos,
                           const int* __restrict__ batch,
                           float2* __restrict__ cs2) {
    __shared__ float kv_s[MJ * 3];
    __shared__ float x_lds[D_PET * MJ];

    if (blockIdx.x >= MLP_BLOCKS) {
        int n = blockIdx.x - MLP_BLOCKS;
        int k = threadIdx.x;
        int b = batch[n];
        float p0 = pos[n * 3 + 0], p1 = pos[n * 3 + 1], p2 = pos[n * 3 + 2];
        const float* kv = kvec + ((size_t)b * NK + k) * 3;
        float ph = p0 * kv[0] + p1 * kv[1] + p2 * kv[2];
        float s, c;
        sincosf(ph, &s, &c);
        cs2[(size_t)n * NK + k] = make_float2(c, s);
        return;
    }

    int bk0 = blockIdx.x * MJ;
    int d   = threadIdx.x & (D_PET - 1);
    int jg  = threadIdx.x >> 7;

    if (threadIdx.x < MJ * 3) kv_s[threadIdx.x] = kvec[bk0 * 3 + threadIdx.x];
    __syncthreads();

    // layer 1: 3 -> 128, silu
    float w10 = W1[0 * D_PET + d], w11 = W1[1 * D_PET + d], w12 = W1[2 * D_PET + d];
    float bb1 = b1[d];
    float4 x1;
    {
        float* xp = (float*)&x1;
#pragma unroll
        for (int i = 0; i < 4; i++) {
            int j = jg * 4 + i;
            float a = bb1;
            a = fmaf(kv_s[j * 3 + 0], w10, a);
            a = fmaf(kv_s[j * 3 + 1], w11, a);
            a = fmaf(kv_s[j * 3 + 2], w12, a);
            xp[i] = silu(a);
        }
    }
    *(float4*)&x_lds[(d << 3) + (jg << 2)] = x1;
    __syncthreads();

    // layer 2: 128 -> 128, silu  (8-wide W batches)
    float acc0 = b2[d], acc1 = acc0, acc2 = acc0, acc3 = acc0;
#pragma unroll
    for (int e0 = 0; e0 < D_PET; e0 += 8) {
        float w[8];
#pragma unroll
        for (int i = 0; i < 8; i++) w[i] = W2[(e0 + i) * D_PET + d];
        __builtin_amdgcn_sched_barrier(0);
#pragma unroll
        for (int i = 0; i < 8; i++) {
            float4 xv = *(const float4*)&x_lds[((e0 + i) << 3) + (jg << 2)];
            acc0 = fmaf(xv.x, w[i], acc0);
            acc1 = fmaf(xv.y, w[i], acc1);
            acc2 = fmaf(xv.z, w[i], acc2);
            acc3 = fmaf(xv.w, w[i], acc3);
        }
    }
    float4 x2 = make_float4(silu(acc0), silu(acc1), silu(acc2), silu(acc3));
    __syncthreads();
    *(float4*)&x_lds[(d << 3) + (jg << 2)] = x2;
    __syncthreads();

    // layer 3: 128 -> 128
    float o0 = b3[d], o1 = o0, o2 = o0, o3 = o0;
#pragma unroll
    for (int e0 = 0; e0 < D_PET; e0 += 8) {
        float w[8];
#pragma unroll
        for (int i = 0; i < 8; i++) w[i] = W3[(e0 + i) * D_PET + d];
        __builtin_amdgcn_sched_barrier(0);
#pragma unroll
        for (int i = 0; i < 8; i++) {
            float4 xv = *(const float4*)&x_lds[((e0 + i) << 3) + (jg << 2)];
            o0 = fmaf(xv.x, w[i], o0);
            o1 = fmaf(xv.y, w[i], o1);
            o2 = fmaf(xv.z, w[i], o2);
            o3 = fmaf(xv.w, w[i], o3);
        }
    }
    float out4[4] = {o0, o1, o2, o3};
#pragma unroll
    for (int i = 0; i < 4; i++) {
        int j = jg * 4 + i;
        filt[(size_t)(bk0 + j) * D_PET + d] = out4[i];
    }
}

// ---------------------------------------------------------------------------
// Kernel 2 (v4): t2[b,k,d] = (sum_n e^{-i phi_nk} h[n,d]) * filt[b,k,d]
// grid = 16*32 = 512 blocks, 256 threads. Thread owns 4 k's x 1 d.
// Atom loop: ping-pong 8-atom chunks, sched_barrier-pinned load clusters
// (24 loads in flight) with prefetch depth 1 (WAR on buffers enforces it).
// ---------------------------------------------------------------------------
#define SKB 8   // k per block

#define S_LOAD(H, C, base)                                                   \
    do {                                                                     \
        _Pragma("unroll")                                                    \
        for (int i_ = 0; i_ < 8; i_++) {                                     \
            H[i_]         = hcol[(size_t)((base) + i_) * D_PET];             \
            C[2 * i_]     = csrow[(size_t)((base) + i_) * (NK / 2)];         \
            C[2 * i_ + 1] = csrow[(size_t)((base) + i_) * (NK / 2) + 1];     \
        }                                                                    \
    } while (0)

#define S_FMA8(H, C)                                                         \
    do {                                                                     \
        _Pragma("unroll")                                                    \
        for (int i_ = 0; i_ < 8; i_++) {                                     \
            float hv = H[i_];                                                \
            float4 qa = C[2 * i_], qb = C[2 * i_ + 1];                       \
            sre[0] = fmaf(qa.x, hv, sre[0]); sim[0] = fmaf(-qa.y, hv, sim[0]); \
            sre[1] = fmaf(qa.z, hv, sre[1]); sim[1] = fmaf(-qa.w, hv, sim[1]); \
            sre[2] = fmaf(qb.x, hv, sre[2]); sim[2] = fmaf(-qb.y, hv, sim[2]); \
            sre[3] = fmaf(qb.z, hv, sre[3]); sim[3] = fmaf(-qb.w, hv, sim[3]); \
        }                                                                    \
    } while (0)

__global__ void __launch_bounds__(256) s_kernel(
                         const float* __restrict__ h,
                         const float* __restrict__ cs2,
                         const int* __restrict__ batch,
                         const float* __restrict__ filt,
                         float2* __restrict__ t2) {
    const int tiles = NK / SKB;                 // 32
    int i = blockIdx.x;
    int v = (i & 7) * (int)(gridDim.x >> 3) + (i >> 3);   // XCD-contiguous
    int b  = v / tiles;
    int k0 = (v % tiles) * SKB;
    int d  = threadIdx.x & (D_PET - 1);
    int kg = threadIdx.x >> 7;                  // 0/1
    int kq = k0 + kg * 4;                       // this thread: k = kq..kq+3

    int lo = lower_bound_dev(batch, NB, b);
    int hi = lower_bound_dev(batch, NB, b + 1);

    const float*  hcol  = h + d;
    const float4* csrow = (const float4*)cs2 + (kq >> 1);

    float sre[4] = {0.f, 0.f, 0.f, 0.f};
    float sim[4] = {0.f, 0.f, 0.f, 0.f};

    float  hA[8], hB[8];
    float4 cAq[16], cBq[16];

    int n = lo;
    if (n + 8 <= hi) {
        S_LOAD(hA, cAq, n);
        bool inA = true;
        int nn = n + 8;
        for (; nn + 8 <= hi; nn += 8) {
            if (inA) { S_LOAD(hB, cBq, nn); __builtin_amdgcn_sched_barrier(0); S_FMA8(hA, cAq); }
            else     { S_LOAD(hA, cAq, nn); __builtin_amdgcn_sched_barrier(0); S_FMA8(hB, cBq); }
            inA = !inA;
        }
        __builtin_amdgcn_sched_barrier(0);
        if (inA) { S_FMA8(hA, cAq); } else { S_FMA8(hB, cBq); }
        n = nn;
    }
    for (; n < hi; n++) {
        float hv = hcol[(size_t)n * D_PET];
        float4 qa = csrow[(size_t)n * (NK / 2)];
        float4 qb = csrow[(size_t)n * (NK / 2) + 1];
        sre[0] = fmaf(qa.x, hv, sre[0]); sim[0] = fmaf(-qa.y, hv, sim[0]);
        sre[1] = fmaf(qa.z, hv, sre[1]); sim[1] = fmaf(-qa.w, hv, sim[1]);
        sre[2] = fmaf(qb.x, hv, sre[2]); sim[2] = fmaf(-qb.y, hv, sim[2]);
        sre[3] = fmaf(qb.z, hv, sre[3]); sim[3] = fmaf(-qb.w, hv, sim[3]);
    }

    size_t idx = ((size_t)b * NK + kq) * D_PET + d;
#pragma unroll
    for (int j = 0; j < 4; j++) {
        float f = filt[idx + (size_t)j * D_PET];
        t2[idx + (size_t)j * D_PET] = make_float2(sre[j] * f, sim[j] * f);
    }
}

// ---------------------------------------------------------------------------
// Kernel 3 (v4): out[n,d] = sum_k e^{+i phi_nk} * t2[batch[n],k,d]
// grid = NB/2 = 1024 blocks, 256 threads. Block owns 2 atoms; k split by
// half-block (ag=0: k<128, ag=1: k>=128) -> t slice read EXACTLY once per
// block for both atoms (256 MB total L2 traffic). Fully-unrolled 16-chunk
// k-loop, ping-pong buffers, sched_barrier-pinned 16-load clusters,
// prefetch depth 1. LDS add combines the two k-halves at the end.
// ---------------------------------------------------------------------------
#define O_LOAD(s, c)                                                         \
    do {                                                                     \
        _Pragma("unroll")                                                    \
        for (int j_ = 0; j_ < 8; j_++)                                       \
            tv[s][j_] = tA[(size_t)(kb + (c) * 8 + j_) * D_PET];             \
        _Pragma("unroll")                                                    \
        for (int j_ = 0; j_ < 4; j_++) {                                     \
            qa[s][j_] = cA4[kb4 + (c) * 4 + j_];                             \
            qb[s][j_] = cB4[kb4 + (c) * 4 + j_];                             \
        }                                                                    \
    } while (0)

#define O_FMA(s)                                                             \
    do {                                                                     \
        _Pragma("unroll")                                                    \
        for (int j_ = 0; j_ < 4; j_++) {                                     \
            float4 q  = qa[s][j_];                                           \
            float2 u0 = tv[s][2 * j_], u1 = tv[s][2 * j_ + 1];               \
            oreA = fmaf(q.x, u0.x, oreA); oreA = fmaf(-q.y, u0.y, oreA);     \
            oimA = fmaf(q.x, u0.y, oimA); oimA = fmaf(q.y, u0.x, oimA);      \
            oreA = fmaf(q.z, u1.x, oreA); oreA = fmaf(-q.w, u1.y, oreA);     \
            oimA = fmaf(q.z, u1.y, oimA); oimA = fmaf(q.w, u1.x, oimA);      \
            q = qb[s][j_];                                                   \
            oreB = fmaf(q.x, u0.x, oreB); oreB = fmaf(-q.y, u0.y, oreB);     \
            oimB = fmaf(q.x, u0.y, oimB); oimB = fmaf(q.y, u0.x, oimB);      \
            oreB = fmaf(q.z, u1.x, oreB); oreB = fmaf(-q.w, u1.y, oreB);     \
            oimB = fmaf(q.z, u1.y, oimB); oimB = fmaf(q.w, u1.x, oimB);      \
        }                                                                    \
    } while (0)

__global__ void __launch_bounds__(256) out_kernel(
                           const float* __restrict__ cs2,
                           const int* __restrict__ batch,
                           const float2* __restrict__ t2,
                           float* __restrict__ out, int interleaved) {
    int i = blockIdx.x;
    int v = (i & 7) * (int)(gridDim.x >> 3) + (i >> 3);   // 1024 blocks
    int d  = threadIdx.x & (D_PET - 1);
    int ag = threadIdx.x >> 7;                  // 0/1 -> k half
    int nA = v * 2, nB = nA + 1;
    int kb  = ag * 128;                         // this half's k base
    int kb4 = ag * 64;                          // in float4 units

    int bA = batch[nA], bB = batch[nB];
    const float2* tA  = t2 + (size_t)bA * NK * D_PET + d;
    const float4* cA4 = (const float4*)(cs2 + (size_t)nA * 2 * NK);
    const float4* cB4 = (const float4*)(cs2 + (size_t)nB * 2 * NK);

    float oreA = 0.f, oimA = 0.f, oreB = 0.f, oimB = 0.f;

    if (bA == bB) {
        float2 tv[2][8];
        float4 qa[2][4], qb[2][4];
        O_LOAD(0, 0);
#pragma unroll
        for (int c = 0; c < 16; c++) {
            if (c + 1 < 16) {
                if (((c + 1) & 1) == 0) { O_LOAD(0, c + 1); } else { O_LOAD(1, c + 1); }
            }
            __builtin_amdgcn_sched_barrier(0);
            if ((c & 1) == 0) { O_FMA(0); } else { O_FMA(1); }
        }
    } else {
        // batch boundary inside the block (rare): dual t streams, single buffer
        const float2* tBp = t2 + (size_t)bB * NK * D_PET + d;
        for (int c = 0; c < 16; c++) {
            float2 ua[8], ub[8];
            float4 pa[4], pb[4];
#pragma unroll
            for (int j = 0; j < 8; j++) {
                ua[j] = tA [(size_t)(kb + c * 8 + j) * D_PET];
                ub[j] = tBp[(size_t)(kb + c * 8 + j) * D_PET];
            }
#pragma unroll
            for (int j = 0; j < 4; j++) {
                pa[j] = cA4[kb4 + c * 4 + j];
                pb[j] = cB4[kb4 + c * 4 + j];
            }
            __builtin_amdgcn_sched_barrier(0);
#pragma unroll
            for (int j = 0; j < 4; j++) {
                float4 q  = pa[j];
                float2 u0 = ua[2 * j], u1 = ua[2 * j + 1];
                oreA = fmaf(q.x, u0.x, oreA); oreA = fmaf(-q.y, u0.y, oreA);
                oimA = fmaf(q.x, u0.y, oimA); oimA = fmaf(q.y, u0.x, oimA);
                oreA = fmaf(q.z, u1.x, oreA); oreA = fmaf(-q.w, u1.y, oreA);
                oimA = fmaf(q.z, u1.y, oimA); oimA = fmaf(q.w, u1.x, oimA);
                q  = pb[j];
                u0 = ub[2 * j]; u1 = ub[2 * j + 1];
                oreB = fmaf(q.x, u0.x, oreB); oreB = fmaf(-q.y, u0.y, oreB);
                oimB = fmaf(q.x, u0.y, oimB); oimB = fmaf(q.y, u0.x, oimB);
                oreB = fmaf(q.z, u1.x, oreB); oreB = fmaf(-q.w, u1.y, oreB);
                oimB = fmaf(q.z, u1.y, oimB); oimB = fmaf(q.w, u1.x, oimB);
            }
        }
    }

    // combine the two k-halves
    __shared__ float red[4][D_PET];
    if (ag == 1) {
        red[0][d] = oreA; red[1][d] = oimA;
        red[2][d] = oreB; red[3][d] = oimB;
    }
    __syncthreads();
    if (ag == 0) {
        oreA += red[0][d]; oimA += red[1][d];
        oreB += red[2][d]; oimB += red[3][d];
        if (interleaved) {
            ((float2*)out)[(size_t)nA * D_PET + d] = make_float2(oreA, oimA);
            ((float2*)out)[(size_t)nB * D_PET + d] = make_float2(oreB, oimB);
        } else {
            out[(size_t)nA * D_PET + d] = oreA;
            out[(size_t)nB * D_PET + d] = oreB;
        }
    }
}

// ---------------------------------------------------------------------------
extern "C" void kernel_launch(void* const* d_in, const int* in_sizes, int n_in,
                              void* d_out, int out_size, void* d_ws, size_t ws_size,
                              hipStream_t stream) {
    const float* kvec = (const float*)d_in[0];
    const float* pos  = (const float*)d_in[1];
    const float* h    = (const float*)d_in[2];
    const float* W1   = (const float*)d_in[3];
    const float* b1   = (const float*)d_in[4];
    const float* W2   = (const float*)d_in[5];
    const float* b2   = (const float*)d_in[6];
    const float* W3   = (const float*)d_in[7];
    const float* b3   = (const float*)d_in[8];
    const int*   batch = (const int*)d_in[9];

    float* ws   = (float*)d_ws;
    float* filt = ws;                                    // 16*256*128 floats
    float* cs2  = filt + (size_t)NBATCH * NK * D_PET;    // 2048*256*2 floats
    float2* t2  = (float2*)(cs2 + (size_t)NB * NK * 2);  // 16*256*128 float2

    int interleaved = (out_size == NB * D_PET * 2) ? 1 : 0;

    prep_kernel<<<MLP_BLOCKS + NB, 256, 0, stream>>>(kvec, W1, b1, W2, b2, W3, b3,
                                                     filt, pos, batch, (float2*)cs2);
    s_kernel<<<NBATCH * (NK / SKB), 256, 0, stream>>>(h, cs2, batch, filt, t2);
    out_kernel<<<NB / 2, 256, 0, stream>>>(cs2, batch, t2, (float*)d_out, interleaved);
}